// Round 8
// baseline (1035.030 us; speedup 1.0000x reference)
//
#include <hip/hip_runtime.h>
#include <hip/hip_bf16.h>

// Window attention (Swin-style), MI355X gfx950. v8: per-head wave ownership.
// Wave h computes q,k,v for head h (v5-proven t-loop mapping), so:
//  - Q/K/P live in a per-head 6272B LDS block, fully wave-private:
//    the B->C and mid-C barriers are GONE.
//  - V stays in registers: the V accumulators are redistributed in-register
//    into PV B-fragments via 32 __shfl (quad gather). VT LDS deleted.
//  - LDS 39440 -> 25088 B; __launch_bounds__(256,5) -> 5 blocks/CU.
//  - 2 barriers total (P-dead -> AO write, AO write -> stage E read).
// af-from-global (v7), swizzles/softmax/stage-E verbatim from proven code.

#define NTOK 49
#define DIMC 128
#define HEADS 4
#define NWM  1024
#define SCALE 0.17677669529663687f

typedef __attribute__((ext_vector_type(8))) __bf16 bf16x8;
typedef __attribute__((ext_vector_type(4))) float f32x4;

// LDS map (bytes):
//  head h block: [h*6272, (h+1)*6272)
//    Q_h [49][64B] @ +0, K_h [49][64B] @ +3136  (stage B -> C, wave-private)
//    P_h [49][128B] @ +0 (aliases Q+K after wave h's qf/kf loads; wave-private)
//  AO [49][256B] @ 0 (aliases P after barrier; cross-wave for stage E)
#define SMEM_BYTES 25088

__device__ __forceinline__ unsigned short f2bf(float f) {
  union { float f; unsigned u; } x; x.f = f;
  unsigned r = x.u + 0x7fffu + ((x.u >> 16) & 1u);   // round-to-nearest-even
  return (unsigned short)(r >> 16);
}

// packed f32x2 -> bf16x2 (low half = first arg), RTNE (proven in v5/v7)
__device__ __forceinline__ unsigned pk2(float a, float b) {
  __hip_bfloat162 t = __float22bfloat162_rn(make_float2(a, b));
  union { __hip_bfloat162 h; unsigned u; } c; c.h = t;
  return c.u;
}

__device__ __forceinline__ f32x4 mfma16(bf16x8 a, bf16x8 b, f32x4 c) {
  return __builtin_amdgcn_mfma_f32_16x16x32_bf16(a, b, c, 0, 0, 0);
}

__device__ __forceinline__ bf16x8 zero8() {
  bf16x8 z;
#pragma unroll
  for (int j = 0; j < 8; ++j) z[j] = (__bf16)0.f;
  return z;
}

// prep: weights -> bf16; rel-pos bias pre-gathered into padded [4][64][64] f32
// with -1e30 outside the 49x49 valid square (kills padding through softmax).
__global__ void winattn_prep(const float* __restrict__ qkv_w,
                             const float* __restrict__ proj_w,
                             const float* __restrict__ table,
                             const int* __restrict__ ridx,
                             unsigned short* __restrict__ qkv_wb,
                             unsigned short* __restrict__ proj_wb,
                             float* __restrict__ bias_g) {
  int i = blockIdx.x * 256 + threadIdx.x;
  if (i < 384 * DIMC) qkv_wb[i] = f2bf(qkv_w[i]);
  if (i < DIMC * DIMC) proj_wb[i] = f2bf(proj_w[i]);
  if (i < HEADS * 64 * 64) {
    int h = i >> 12, n = (i >> 6) & 63, m = i & 63;
    float v = -1e30f;
    if (n < NTOK && m < NTOK) v = table[ridx[n * NTOK + m] * HEADS + h];
    bias_g[i] = v;
  }
}

__launch_bounds__(256, 5)
__global__ void winattn_main(const float* __restrict__ x,
                             const float* __restrict__ mask,
                             const unsigned short* __restrict__ qkv_wb,
                             const float* __restrict__ qkv_b,
                             const unsigned short* __restrict__ proj_wb,
                             const float* __restrict__ proj_b,
                             const float* __restrict__ bias_g,
                             float* __restrict__ out) {
  __shared__ char smem[SMEM_BYTES] __attribute__((aligned(128)));
  const int tid  = threadIdx.x;
  const int w    = blockIdx.x;
  const int lane = tid & 63;
  const int wid  = tid >> 6;
  const int lr   = lane & 15;
  const int lg   = lane >> 4;
  const int h    = wid;                       // wave == head
  const int hb   = h * 6272;                  // per-head LDS block base
  const f32x4 fzero = {0.f, 0.f, 0.f, 0.f};

  const float* xw = x + (size_t)w * (NTOK * DIMC);

  // ---------- af fragments directly from global x (v7 verbatim) -----------
  bf16x8 af[4][4];
#pragma unroll
  for (int mt = 0; mt < 4; ++mt)
#pragma unroll
    for (int kk = 0; kk < 4; ++kk) {
      int n = mt * 16 + lr;
      bool pad = (n > 48);
      int nc = pad ? 48 : n;
      const float* src = xw + nc * DIMC + kk * 32 + lg * 8;
      float4 v0 = *reinterpret_cast<const float4*>(src);
      float4 v1 = *reinterpret_cast<const float4*>(src + 4);
      uint4 d;
      d.x = pk2(v0.x, v0.y); d.y = pk2(v0.z, v0.w);
      d.z = pk2(v1.x, v1.y); d.w = pk2(v1.z, v1.w);
      union { uint4 u; bf16x8 b; } cvt; cvt.u = d;
      af[mt][kk] = pad ? zero8() : cvt.b;
    }

  // ---------- Stage B: wave h computes q,k,v of head h --------------------
  bf16x8 vb[2][2];   // PV B-fragments, built in-register from V accs
#pragma unroll
  for (int t = 0; t < 6; ++t) {
    const int sec  = t >> 1;                   // 0=q 1=k 2=v
    const int half = t & 1;                    // d-half (0..15 / 16..31)
    const int o0   = sec * 128 + 32 * h + 16 * half;
    const unsigned short* wrow = qkv_wb + (o0 + lr) * DIMC;
    bf16x8 wf[4];
#pragma unroll
    for (int kk = 0; kk < 4; ++kk)
      wf[kk] = *reinterpret_cast<const bf16x8*>(wrow + kk * 32 + 8 * lg);
    f32x4 acc[4];
#pragma unroll
    for (int mt = 0; mt < 4; ++mt) acc[mt] = fzero;
#pragma unroll
    for (int kk = 0; kk < 4; ++kk)
#pragma unroll
      for (int mt = 0; mt < 4; ++mt)
        acc[mt] = mfma16(af[mt][kk], wf[kk], acc[mt]);   // unswapped (proven)
    const float bq = qkv_b[o0 + lr];
    const int d = 16 * half + lr;              // qkv feature col of this lane
    if (sec < 2) {
      // scalar epilogue (v4-proven) into per-head Q/K block
      const int base = hb + ((sec == 1) ? 3136 : 0);
#pragma unroll
      for (int mt = 0; mt < 4; ++mt)
#pragma unroll
        for (int r = 0; r < 4; ++r) {
          const int n = mt * 16 + lg * 4 + r;  // token
          if (n < NTOK) {
            int mb = (d * 2) ^ ((n & 3) << 4);
            *reinterpret_cast<unsigned short*>(smem + base + n * 64 + mb) =
                f2bf(acc[mt][r] + bq);
          }
        }
    } else {
      // V-in-register: pack quads, shfl-gather into vb[half][kk].
      // acc[mt][r] = V[token mt*16+lg*4+r][d]; tokens>=49 finite garbage,
      // killed by P[:,m>=49]==0 in the PV MFMA.
      uint2 pk[4];
#pragma unroll
      for (int mt = 0; mt < 4; ++mt) {
        pk[mt].x = pk2(acc[mt][0] + bq, acc[mt][1] + bq);
        pk[mt].y = pk2(acc[mt][2] + bq, acc[mt][3] + bq);
      }
      // target lane (lr,lg) wants V^T[d' = 16*half + lr][tokens kk*32+lg*8..+7]
      // low quad  <- lane lr + 16*((2lg  )&3), mt = kk*2 + (lg>>1)
      // high quad <- lane lr + 16*((2lg+1)&3), mt = kk*2 + (lg>>1)
      const int srcLow  = lr + ((lg & 1) ? 32 : 0);
      const int srcHigh = srcLow + 16;
      const bool hiSel  = (lg >> 1) != 0;
#pragma unroll
      for (int kk = 0; kk < 2; ++kk) {
        unsigned a0x = __shfl(pk[kk * 2].x, srcLow);
        unsigned a0y = __shfl(pk[kk * 2].y, srcLow);
        unsigned a1x = __shfl(pk[kk * 2 + 1].x, srcLow);
        unsigned a1y = __shfl(pk[kk * 2 + 1].y, srcLow);
        unsigned b0x = __shfl(pk[kk * 2].x, srcHigh);
        unsigned b0y = __shfl(pk[kk * 2].y, srcHigh);
        unsigned b1x = __shfl(pk[kk * 2 + 1].x, srcHigh);
        unsigned b1y = __shfl(pk[kk * 2 + 1].y, srcHigh);
        union { uint4 u; bf16x8 b; } cvt;
        cvt.u.x = hiSel ? a1x : a0x;
        cvt.u.y = hiSel ? a1y : a0y;
        cvt.u.z = hiSel ? b1x : b0x;
        cvt.u.w = hiSel ? b1y : b0y;
        vb[half][kk] = cvt.b;
      }
    }
  }
  // Q/K/P/vb all wave-private -> NO barrier

  // ---------- Stage C: scores + softmax (wave-private) --------------------
  {
    bf16x8 qf[4], kf[4];
#pragma unroll
    for (int mt = 0; mt < 4; ++mt) {
      int n = mt * 16 + lr; if (n > 48) n = 48;   // clamp padded rows
      int mb = (lg * 16) ^ ((n & 3) << 4);
      qf[mt] = *reinterpret_cast<const bf16x8*>(smem + hb + n * 64 + mb);
    }
#pragma unroll
    for (int nt = 0; nt < 4; ++nt) {
      int m = nt * 16 + lr; if (m > 48) m = 48;
      int mb = (lg * 16) ^ ((m & 3) << 4);
      kf[nt] = *reinterpret_cast<const bf16x8*>(smem + hb + 3136 + m * 64 + mb);
    }
    f32x4 sc[4][4];
#pragma unroll
    for (int mt = 0; mt < 4; ++mt)
#pragma unroll
      for (int nt = 0; nt < 4; ++nt)
        sc[mt][nt] = mfma16(qf[mt], kf[nt], fzero);

    const float* bgh = bias_g + h * 4096;
    const float* mw  = mask + (size_t)(w & (NWM - 1)) * (NTOK * NTOK);
#pragma unroll
    for (int mt = 0; mt < 4; ++mt)
#pragma unroll
      for (int r = 0; r < 4; ++r) {
        const int n  = mt * 16 + lg * 4 + r;
        const int nc = (n > 48) ? 48 : n;
#pragma unroll
        for (int nt = 0; nt < 4; ++nt) {
          const int m  = nt * 16 + lr;
          const int mc = (m > 48) ? 48 : m;
          sc[mt][nt][r] = sc[mt][nt][r] * SCALE + bgh[n * 64 + m] + mw[nc * NTOK + mc];
        }
      }
    // NO barrier: P aliases this wave's own Q/K only (per-head block);
    // same-wave DS ordering + may-alias keeps store-after-load safe.

    // softmax per row n: 4 in-lane (nt) + shfl_xor over the 16-lane group
#pragma unroll
    for (int mt = 0; mt < 4; ++mt)
#pragma unroll
      for (int r = 0; r < 4; ++r) {
        float mx = sc[mt][0][r];
#pragma unroll
        for (int nt = 1; nt < 4; ++nt) mx = fmaxf(mx, sc[mt][nt][r]);
        mx = fmaxf(mx, __shfl_xor(mx, 1, 16));
        mx = fmaxf(mx, __shfl_xor(mx, 2, 16));
        mx = fmaxf(mx, __shfl_xor(mx, 4, 16));
        mx = fmaxf(mx, __shfl_xor(mx, 8, 16));
        float e[4]; float sum = 0.f;
#pragma unroll
        for (int nt = 0; nt < 4; ++nt) { e[nt] = __expf(sc[mt][nt][r] - mx); sum += e[nt]; }
        sum += __shfl_xor(sum, 1, 16);
        sum += __shfl_xor(sum, 2, 16);
        sum += __shfl_xor(sum, 4, 16);
        sum += __shfl_xor(sum, 8, 16);
        const float inv = __builtin_amdgcn_rcpf(sum);
        const int n = mt * 16 + lg * 4 + r;
        if (n < NTOK) {
#pragma unroll
          for (int nt = 0; nt < 4; ++nt) {
            const int m = nt * 16 + lr;
            int mb = (m * 2) ^ ((n & 7) << 4);
            *reinterpret_cast<unsigned short*>(smem + hb + n * 128 + mb) =
                f2bf(e[nt] * inv);   // P_h (aliases Q_h+K_h; wave-private)
          }
        }
      }
  }

  // ---------- Stage D: PV with in-register V ------------------------------
  {
    bf16x8 pa[4][2];
#pragma unroll
    for (int mt = 0; mt < 4; ++mt)
#pragma unroll
      for (int kk = 0; kk < 2; ++kk) {
        int n = mt * 16 + lr; if (n > 48) n = 48;
        int mb = (kk * 64 + lg * 16) ^ ((n & 7) << 4);
        pa[mt][kk] = *reinterpret_cast<const bf16x8*>(smem + hb + n * 128 + mb);
      }
    f32x4 oc[4][2];
#pragma unroll
    for (int mt = 0; mt < 4; ++mt)
#pragma unroll
      for (int dt = 0; dt < 2; ++dt) oc[mt][dt] = fzero;
#pragma unroll
    for (int kk = 0; kk < 2; ++kk)
#pragma unroll
      for (int mt = 0; mt < 4; ++mt)
#pragma unroll
        for (int dt = 0; dt < 2; ++dt)
          oc[mt][dt] = mfma16(pa[mt][kk], vb[dt][kk], oc[mt][dt]);
    __syncthreads();   // all waves past their P reads -> AO may alias P
#pragma unroll
    for (int mt = 0; mt < 4; ++mt)
#pragma unroll
      for (int dt = 0; dt < 2; ++dt)
#pragma unroll
        for (int r = 0; r < 4; ++r) {
          const int n = mt * 16 + lg * 4 + r;
          if (n < NTOK) {
            const int c = h * 32 + dt * 16 + lr;
            int mb = (c * 2) ^ ((n & 7) << 4);
            *reinterpret_cast<unsigned short*>(smem + n * 256 + mb) =
                f2bf(oc[mt][dt][r]);   // AO @ base 0
          }
        }
  }
  __syncthreads();

  // ---------- Stage E: proj = AO @ proj_w^T + proj_b (v7, base 0) ---------
  {
    bf16x8 aof[4][4];
#pragma unroll
    for (int mt = 0; mt < 4; ++mt)
#pragma unroll
      for (int kk = 0; kk < 4; ++kk) {
        int n = mt * 16 + lr; if (n > 48) n = 48;      // keep in AO bounds
        int s16 = 4 * kk + lg;
        aof[mt][kk] = *reinterpret_cast<const bf16x8*>(
            smem + n * 256 + (((s16 & 8) | ((s16 ^ (n & 7)) & 7)) << 4));
      }
    float* ow = out + (size_t)w * (NTOK * DIMC);
#pragma unroll
    for (int ct = 0; ct < 2; ++ct) {
      const int c = (wid * 2 + ct) * 16 + lr;  // each wave owns 32 cols
      const unsigned short* wrow = proj_wb + c * DIMC;
      bf16x8 wb[4];
#pragma unroll
      for (int kk = 0; kk < 4; ++kk)
        wb[kk] = *reinterpret_cast<const bf16x8*>(wrow + kk * 32 + lg * 8);
      f32x4 acc[4];
#pragma unroll
      for (int mt = 0; mt < 4; ++mt) acc[mt] = fzero;
#pragma unroll
      for (int kk = 0; kk < 4; ++kk)
#pragma unroll
        for (int mt = 0; mt < 4; ++mt)
          acc[mt] = mfma16(aof[mt][kk], wb[kk], acc[mt]);
      const float bp = proj_b[c];
#pragma unroll
      for (int mt = 0; mt < 4; ++mt)
#pragma unroll
        for (int r = 0; r < 4; ++r) {
          const int n = mt * 16 + lg * 4 + r;
          if (n < NTOK) ow[n * DIMC + c] = acc[mt][r] + bp;
        }
    }
  }
}

extern "C" void kernel_launch(void* const* d_in, const int* in_sizes, int n_in,
                              void* d_out, int out_size, void* d_ws, size_t ws_size,
                              hipStream_t stream) {
  const float* x      = (const float*)d_in[0];
  const float* mask   = (const float*)d_in[1];
  const float* qkv_w  = (const float*)d_in[2];
  const float* qkv_b  = (const float*)d_in[3];
  const float* proj_w = (const float*)d_in[4];
  const float* proj_b = (const float*)d_in[5];
  const float* table  = (const float*)d_in[6];
  const int*   ridx   = (const int*)d_in[7];

  unsigned short* qkv_wb  = (unsigned short*)d_ws;           // 384*128 bf16
  unsigned short* proj_wb = qkv_wb + 384 * DIMC;             // 128*128 bf16
  float*          bias_g  = (float*)(proj_wb + DIMC * DIMC); // [4][64][64] f32

  winattn_prep<<<192, 256, 0, stream>>>(qkv_w, proj_w, table, ridx,
                                        qkv_wb, proj_wb, bias_g);

  const int nwin = in_sizes[0] / (NTOK * DIMC);
  winattn_main<<<nwin, 256, 0, stream>>>(x, mask, qkv_wb, qkv_b, proj_wb,
                                         proj_b, bias_g, (float*)d_out);
}

// Round 9
// 704.590 us; speedup vs baseline: 1.4690x; 1.4690x over previous
//
#include <hip/hip_runtime.h>
#include <hip/hip_bf16.h>

// Window attention (Swin-style), MI355X gfx950. v9 = v8 structure with the
// register cap fixed: __launch_bounds__(256,4) (v8's (256,5) forced VGPR=48,
// causing af-remat from global -> 3.7x FETCH). Stage E = v5-proven swapped
// MFMA + float4 global stores. All else byte-identical to v8:
//  - wave h owns head h; Q/K/P in per-head 6272B LDS block (wave-private,
//    no B->C or mid-C barrier)
//  - V never in LDS: shfl quad-gather into PV B-fragments
//  - 2 barriers total; LDS 25088 B

#define NTOK 49
#define DIMC 128
#define HEADS 4
#define NWM  1024
#define SCALE 0.17677669529663687f

typedef __attribute__((ext_vector_type(8))) __bf16 bf16x8;
typedef __attribute__((ext_vector_type(4))) float f32x4;

#define SMEM_BYTES 25088

__device__ __forceinline__ unsigned short f2bf(float f) {
  union { float f; unsigned u; } x; x.f = f;
  unsigned r = x.u + 0x7fffu + ((x.u >> 16) & 1u);   // round-to-nearest-even
  return (unsigned short)(r >> 16);
}

__device__ __forceinline__ unsigned pk2(float a, float b) {
  __hip_bfloat162 t = __float22bfloat162_rn(make_float2(a, b));
  union { __hip_bfloat162 h; unsigned u; } c; c.h = t;
  return c.u;
}

__device__ __forceinline__ f32x4 mfma16(bf16x8 a, bf16x8 b, f32x4 c) {
  return __builtin_amdgcn_mfma_f32_16x16x32_bf16(a, b, c, 0, 0, 0);
}

__device__ __forceinline__ bf16x8 zero8() {
  bf16x8 z;
#pragma unroll
  for (int j = 0; j < 8; ++j) z[j] = (__bf16)0.f;
  return z;
}

// prep: weights -> bf16; rel-pos bias pre-gathered into padded [4][64][64] f32
// with -1e30 outside the 49x49 valid square (kills padding through softmax).
__global__ void winattn_prep(const float* __restrict__ qkv_w,
                             const float* __restrict__ proj_w,
                             const float* __restrict__ table,
                             const int* __restrict__ ridx,
                             unsigned short* __restrict__ qkv_wb,
                             unsigned short* __restrict__ proj_wb,
                             float* __restrict__ bias_g) {
  int i = blockIdx.x * 256 + threadIdx.x;
  if (i < 384 * DIMC) qkv_wb[i] = f2bf(qkv_w[i]);
  if (i < DIMC * DIMC) proj_wb[i] = f2bf(proj_w[i]);
  if (i < HEADS * 64 * 64) {
    int h = i >> 12, n = (i >> 6) & 63, m = i & 63;
    float v = -1e30f;
    if (n < NTOK && m < NTOK) v = table[ridx[n * NTOK + m] * HEADS + h];
    bias_g[i] = v;
  }
}

__launch_bounds__(256, 4)
__global__ void winattn_main(const float* __restrict__ x,
                             const float* __restrict__ mask,
                             const unsigned short* __restrict__ qkv_wb,
                             const float* __restrict__ qkv_b,
                             const unsigned short* __restrict__ proj_wb,
                             const float* __restrict__ proj_b,
                             const float* __restrict__ bias_g,
                             float* __restrict__ out) {
  __shared__ char smem[SMEM_BYTES] __attribute__((aligned(128)));
  const int tid  = threadIdx.x;
  const int w    = blockIdx.x;
  const int lane = tid & 63;
  const int wid  = tid >> 6;
  const int lr   = lane & 15;
  const int lg   = lane >> 4;
  const int h    = wid;                       // wave == head
  const int hb   = h * 6272;                  // per-head LDS block base
  const f32x4 fzero = {0.f, 0.f, 0.f, 0.f};

  const float* xw = x + (size_t)w * (NTOK * DIMC);

  // ---------- af fragments directly from global x (v7 verbatim) -----------
  bf16x8 af[4][4];
#pragma unroll
  for (int mt = 0; mt < 4; ++mt)
#pragma unroll
    for (int kk = 0; kk < 4; ++kk) {
      int n = mt * 16 + lr;
      bool pad = (n > 48);
      int nc = pad ? 48 : n;
      const float* src = xw + nc * DIMC + kk * 32 + lg * 8;
      float4 v0 = *reinterpret_cast<const float4*>(src);
      float4 v1 = *reinterpret_cast<const float4*>(src + 4);
      uint4 d;
      d.x = pk2(v0.x, v0.y); d.y = pk2(v0.z, v0.w);
      d.z = pk2(v1.x, v1.y); d.w = pk2(v1.z, v1.w);
      union { uint4 u; bf16x8 b; } cvt; cvt.u = d;
      af[mt][kk] = pad ? zero8() : cvt.b;
    }

  // ---------- Stage B: wave h computes q,k,v of head h --------------------
  bf16x8 vb[2][2];   // PV B-fragments, built in-register from V accs
#pragma unroll
  for (int t = 0; t < 6; ++t) {
    const int sec  = t >> 1;                   // 0=q 1=k 2=v
    const int half = t & 1;                    // d-half (0..15 / 16..31)
    const int o0   = sec * 128 + 32 * h + 16 * half;
    const unsigned short* wrow = qkv_wb + (o0 + lr) * DIMC;
    bf16x8 wf[4];
#pragma unroll
    for (int kk = 0; kk < 4; ++kk)
      wf[kk] = *reinterpret_cast<const bf16x8*>(wrow + kk * 32 + 8 * lg);
    f32x4 acc[4];
#pragma unroll
    for (int mt = 0; mt < 4; ++mt) acc[mt] = fzero;
#pragma unroll
    for (int kk = 0; kk < 4; ++kk)
#pragma unroll
      for (int mt = 0; mt < 4; ++mt)
        acc[mt] = mfma16(af[mt][kk], wf[kk], acc[mt]);   // unswapped (proven)
    const float bq = qkv_b[o0 + lr];
    const int d = 16 * half + lr;              // qkv feature col of this lane
    if (sec < 2) {
      // scalar epilogue (v4-proven) into per-head Q/K block
      const int base = hb + ((sec == 1) ? 3136 : 0);
#pragma unroll
      for (int mt = 0; mt < 4; ++mt)
#pragma unroll
        for (int r = 0; r < 4; ++r) {
          const int n = mt * 16 + lg * 4 + r;  // token
          if (n < NTOK) {
            int mb = (d * 2) ^ ((n & 3) << 4);
            *reinterpret_cast<unsigned short*>(smem + base + n * 64 + mb) =
                f2bf(acc[mt][r] + bq);
          }
        }
    } else {
      // V-in-register: pack quads, shfl-gather into vb[half][kk].
      uint2 pk[4];
#pragma unroll
      for (int mt = 0; mt < 4; ++mt) {
        pk[mt].x = pk2(acc[mt][0] + bq, acc[mt][1] + bq);
        pk[mt].y = pk2(acc[mt][2] + bq, acc[mt][3] + bq);
      }
      // target lane (lr,lg) wants V^T[d'=16*half+lr][tokens kk*32+lg*8..+7]
      const int srcLow  = lr + ((lg & 1) ? 32 : 0);
      const int srcHigh = srcLow + 16;
      const bool hiSel  = (lg >> 1) != 0;
#pragma unroll
      for (int kk = 0; kk < 2; ++kk) {
        unsigned a0x = __shfl(pk[kk * 2].x, srcLow);
        unsigned a0y = __shfl(pk[kk * 2].y, srcLow);
        unsigned a1x = __shfl(pk[kk * 2 + 1].x, srcLow);
        unsigned a1y = __shfl(pk[kk * 2 + 1].y, srcLow);
        unsigned b0x = __shfl(pk[kk * 2].x, srcHigh);
        unsigned b0y = __shfl(pk[kk * 2].y, srcHigh);
        unsigned b1x = __shfl(pk[kk * 2 + 1].x, srcHigh);
        unsigned b1y = __shfl(pk[kk * 2 + 1].y, srcHigh);
        union { uint4 u; bf16x8 b; } cvt;
        cvt.u.x = hiSel ? a1x : a0x;
        cvt.u.y = hiSel ? a1y : a0y;
        cvt.u.z = hiSel ? b1x : b0x;
        cvt.u.w = hiSel ? b1y : b0y;
        vb[half][kk] = cvt.b;
      }
    }
  }
  // Q/K/P/vb all wave-private -> NO barrier

  // ---------- Stage C: scores + softmax (wave-private) --------------------
  {
    bf16x8 qf[4], kf[4];
#pragma unroll
    for (int mt = 0; mt < 4; ++mt) {
      int n = mt * 16 + lr; if (n > 48) n = 48;   // clamp padded rows
      int mb = (lg * 16) ^ ((n & 3) << 4);
      qf[mt] = *reinterpret_cast<const bf16x8*>(smem + hb + n * 64 + mb);
    }
#pragma unroll
    for (int nt = 0; nt < 4; ++nt) {
      int m = nt * 16 + lr; if (m > 48) m = 48;
      int mb = (lg * 16) ^ ((m & 3) << 4);
      kf[nt] = *reinterpret_cast<const bf16x8*>(smem + hb + 3136 + m * 64 + mb);
    }
    f32x4 sc[4][4];
#pragma unroll
    for (int mt = 0; mt < 4; ++mt)
#pragma unroll
      for (int nt = 0; nt < 4; ++nt)
        sc[mt][nt] = mfma16(qf[mt], kf[nt], fzero);

    const float* bgh = bias_g + h * 4096;
    const float* mw  = mask + (size_t)(w & (NWM - 1)) * (NTOK * NTOK);
#pragma unroll
    for (int mt = 0; mt < 4; ++mt)
#pragma unroll
      for (int r = 0; r < 4; ++r) {
        const int n  = mt * 16 + lg * 4 + r;
        const int nc = (n > 48) ? 48 : n;
#pragma unroll
        for (int nt = 0; nt < 4; ++nt) {
          const int m  = nt * 16 + lr;
          const int mc = (m > 48) ? 48 : m;
          sc[mt][nt][r] = sc[mt][nt][r] * SCALE + bgh[n * 64 + m] + mw[nc * NTOK + mc];
        }
      }
    // NO barrier: P aliases this wave's own Q/K only; same-wave DS ordering.

    // softmax per row n: 4 in-lane (nt) + shfl_xor over the 16-lane group
#pragma unroll
    for (int mt = 0; mt < 4; ++mt)
#pragma unroll
      for (int r = 0; r < 4; ++r) {
        float mx = sc[mt][0][r];
#pragma unroll
        for (int nt = 1; nt < 4; ++nt) mx = fmaxf(mx, sc[mt][nt][r]);
        mx = fmaxf(mx, __shfl_xor(mx, 1, 16));
        mx = fmaxf(mx, __shfl_xor(mx, 2, 16));
        mx = fmaxf(mx, __shfl_xor(mx, 4, 16));
        mx = fmaxf(mx, __shfl_xor(mx, 8, 16));
        float e[4]; float sum = 0.f;
#pragma unroll
        for (int nt = 0; nt < 4; ++nt) { e[nt] = __expf(sc[mt][nt][r] - mx); sum += e[nt]; }
        sum += __shfl_xor(sum, 1, 16);
        sum += __shfl_xor(sum, 2, 16);
        sum += __shfl_xor(sum, 4, 16);
        sum += __shfl_xor(sum, 8, 16);
        const float inv = __builtin_amdgcn_rcpf(sum);
        const int n = mt * 16 + lg * 4 + r;
        if (n < NTOK) {
#pragma unroll
          for (int nt = 0; nt < 4; ++nt) {
            const int m = nt * 16 + lr;
            int mb = (m * 2) ^ ((n & 7) << 4);
            *reinterpret_cast<unsigned short*>(smem + hb + n * 128 + mb) =
                f2bf(e[nt] * inv);   // P_h (aliases Q_h+K_h; wave-private)
          }
        }
      }
  }

  // ---------- Stage D: PV with in-register V ------------------------------
  {
    bf16x8 pa[4][2];
#pragma unroll
    for (int mt = 0; mt < 4; ++mt)
#pragma unroll
      for (int kk = 0; kk < 2; ++kk) {
        int n = mt * 16 + lr; if (n > 48) n = 48;
        int mb = (kk * 64 + lg * 16) ^ ((n & 7) << 4);
        pa[mt][kk] = *reinterpret_cast<const bf16x8*>(smem + hb + n * 128 + mb);
      }
    f32x4 oc[4][2];
#pragma unroll
    for (int mt = 0; mt < 4; ++mt)
#pragma unroll
      for (int dt = 0; dt < 2; ++dt) oc[mt][dt] = fzero;
#pragma unroll
    for (int kk = 0; kk < 2; ++kk)
#pragma unroll
      for (int mt = 0; mt < 4; ++mt)
#pragma unroll
        for (int dt = 0; dt < 2; ++dt)
          oc[mt][dt] = mfma16(pa[mt][kk], vb[dt][kk], oc[mt][dt]);
    __syncthreads();   // all waves past their P reads -> AO may alias P
#pragma unroll
    for (int mt = 0; mt < 4; ++mt)
#pragma unroll
      for (int dt = 0; dt < 2; ++dt)
#pragma unroll
        for (int r = 0; r < 4; ++r) {
          const int n = mt * 16 + lg * 4 + r;
          if (n < NTOK) {
            const int c = h * 32 + dt * 16 + lr;
            int mb = (c * 2) ^ ((n & 7) << 4);
            *reinterpret_cast<unsigned short*>(smem + n * 256 + mb) =
                f2bf(oc[mt][dt][r]);   // AO @ base 0
          }
        }
  }
  __syncthreads();

  // ---------- Stage E: proj, swapped -> float4 global stores (v5-proven) --
  {
    bf16x8 aof[4][4];
#pragma unroll
    for (int nt = 0; nt < 4; ++nt)
#pragma unroll
      for (int kk = 0; kk < 4; ++kk) {
        int n = nt * 16 + lr; if (n > 48) n = 48;      // keep in AO bounds
        int s16 = 4 * kk + lg;
        aof[nt][kk] = *reinterpret_cast<const bf16x8*>(
            smem + n * 256 + (((s16 & 8) | ((s16 ^ (n & 7)) & 7)) << 4));
      }
    float* ow = out + (size_t)w * (NTOK * DIMC);
#pragma unroll
    for (int ct = 0; ct < 2; ++ct) {
      const int c0s = (wid * 2 + ct) * 16;   // 16-col tile base
      const unsigned short* wrow = proj_wb + (c0s + lr) * DIMC;
      bf16x8 wf2[4];
#pragma unroll
      for (int kk = 0; kk < 4; ++kk)
        wf2[kk] = *reinterpret_cast<const bf16x8*>(wrow + kk * 32 + lg * 8);
      f32x4 acc[4];
#pragma unroll
      for (int nt = 0; nt < 4; ++nt) acc[nt] = fzero;
      // swapped: acc row = c (4 consec per lane), col = token n (lr)
#pragma unroll
      for (int kk = 0; kk < 4; ++kk)
#pragma unroll
        for (int nt = 0; nt < 4; ++nt)
          acc[nt] = mfma16(wf2[kk], aof[nt][kk], acc[nt]);
      float4 bp = *reinterpret_cast<const float4*>(proj_b + c0s + 4 * lg);
#pragma unroll
      for (int nt = 0; nt < 4; ++nt) {
        int n = nt * 16 + lr;
        if (n < NTOK) {
          float4 o;
          o.x = acc[nt][0] + bp.x; o.y = acc[nt][1] + bp.y;
          o.z = acc[nt][2] + bp.z; o.w = acc[nt][3] + bp.w;
          *reinterpret_cast<float4*>(ow + n * DIMC + c0s + 4 * lg) = o;
        }
      }
    }
  }
}

extern "C" void kernel_launch(void* const* d_in, const int* in_sizes, int n_in,
                              void* d_out, int out_size, void* d_ws, size_t ws_size,
                              hipStream_t stream) {
  const float* x      = (const float*)d_in[0];
  const float* mask   = (const float*)d_in[1];
  const float* qkv_w  = (const float*)d_in[2];
  const float* qkv_b  = (const float*)d_in[3];
  const float* proj_w = (const float*)d_in[4];
  const float* proj_b = (const float*)d_in[5];
  const float* table  = (const float*)d_in[6];
  const int*   ridx   = (const int*)d_in[7];

  unsigned short* qkv_wb  = (unsigned short*)d_ws;           // 384*128 bf16
  unsigned short* proj_wb = qkv_wb + 384 * DIMC;             // 128*128 bf16
  float*          bias_g  = (float*)(proj_wb + DIMC * DIMC); // [4][64][64] f32

  winattn_prep<<<192, 256, 0, stream>>>(qkv_w, proj_w, table, ridx,
                                        qkv_wb, proj_wb, bias_g);

  const int nwin = in_sizes[0] / (NTOK * DIMC);
  winattn_main<<<nwin, 256, 0, stream>>>(x, mask, qkv_wb, qkv_b, proj_wb,
                                         proj_b, bias_g, (float*)d_out);
}